// Round 3
// 1078.397 us; speedup vs baseline: 1.0792x; 1.0792x over previous
//
#include <hip/hip_runtime.h>

typedef __bf16 bf16x8 __attribute__((ext_vector_type(8)));
typedef float f32x4 __attribute__((ext_vector_type(4)));
typedef unsigned short u16;
typedef unsigned int u32;

#define MFMA(a, b, c) __builtin_amdgcn_mfma_f32_16x16x32_bf16((a), (b), (c), 0, 0, 0)

// B=2, L=2048, D=1024, H=16, DH=64
// d_out: out [B,L,D] (4,194,304 f32) then attn [B,H,L,L] (134,217,728 f32)

__device__ __forceinline__ u16 f2bf(float f) {
  u32 u = __float_as_uint(f);
  return (u16)((u + 0x7fffu + ((u >> 16) & 1u)) >> 16);
}

// ---------------- merged prep: 5x fp32->bf16 convert + conv weight transpose ----------------
// blocks [0,4096) src; [4096,5120) Wq; [5120,6144) Wk; [6144,7168) Wv; [7168,8192) Wo;
// blocks [8192,8384) transpose conv_w [H,D,3] -> [H,3,D]
__global__ __launch_bounds__(256) void prep_all(
    const float4* __restrict__ src, const float4* __restrict__ wq,
    const float4* __restrict__ wk, const float4* __restrict__ wv,
    const float4* __restrict__ wo, const float* __restrict__ cw,
    uint2* __restrict__ srcb, uint2* __restrict__ wqb, uint2* __restrict__ wkb,
    uint2* __restrict__ wvb, uint2* __restrict__ wob, float* __restrict__ cwT) {
  int bx = blockIdx.x;
  if (bx < 8192) {
    const float4* in;
    uint2* out;
    int base;
    if (bx < 4096) { in = src; out = srcb; base = 0; }
    else if (bx < 5120) { in = wq; out = wqb; base = 4096; }
    else if (bx < 6144) { in = wk; out = wkb; base = 5120; }
    else if (bx < 7168) { in = wv; out = wvb; base = 6144; }
    else { in = wo; out = wob; base = 7168; }
    int i = (bx - base) * 256 + threadIdx.x;
    float4 v = in[i];
    uint2 o;
    o.x = (u32)f2bf(v.x) | ((u32)f2bf(v.y) << 16);
    o.y = (u32)f2bf(v.z) | ((u32)f2bf(v.w) << 16);
    out[i] = o;
  } else {
    int i = (bx - 8192) * 256 + threadIdx.x;
    int h = i / 3072;
    int j = (i - h * 3072) >> 10;
    int d = i & 1023;
    cwT[i] = cw[(h * 1024 + d) * 3 + j];
  }
}

// ---------------- saliency conv: sal[b,h,l] = sum_{j,d} src[b,l+j-1,d]*w[h,d,j] + cb[h]
// float4 accumulator -> 4 independent FMA chains (was one 3072-deep dependent chain)
__global__ __launch_bounds__(256) void conv_sal_k(const float* __restrict__ src,
                                                  const float* __restrict__ cwT,
                                                  const float* __restrict__ cb,
                                                  float* __restrict__ sal) {
  const int t = threadIdx.x;
  const int h = t & 15, li = t >> 4;
  const int b = blockIdx.y;
  const int l = blockIdx.x * 16 + li;
  float4 acc = {0.f, 0.f, 0.f, 0.f};
#pragma unroll
  for (int j = 0; j < 3; j++) {
    int ls = l + j - 1;
    if (ls < 0 || ls >= 2048) continue;
    const float4* sp = (const float4*)(src + ((size_t)b * 2048 + ls) * 1024);
    const float4* wp = (const float4*)(cwT + (h * 3 + j) * 1024);
    for (int d = 0; d < 256; d++) {
      float4 a = sp[d], w = wp[d];
      acc.x += a.x * w.x;
      acc.y += a.y * w.y;
      acc.z += a.z * w.z;
      acc.w += a.w * w.w;
    }
  }
  sal[(b * 16 + h) * 2048 + l] = cb[h] + ((acc.x + acc.y) + (acc.z + acc.w));
}

// ---------------- LDS-tiled GEMM core: 128x128 tile, BK=32, reg-staged (global->reg->ds_write)
// Y = X @ W^T ; X [M,1024] bf16 row-major, W [N,1024] bf16 row-major. acc = 4x4 f32x4 per wave.
// LDS layout: row-major [128][32] u16 per operand; thread t stages 16B chunk (row t>>2, k (t&3)*8)
// at byte offset t*16 (and row+64 at +4096B). Read side: wave frag = row (subtile+i*16+cl),
// k = gp*8 -> identical mapping to the register-direct round-0 kernel (verified).
__device__ __forceinline__ void gemm_core(const u16* __restrict__ Xg, const u16* __restrict__ Wg,
                                          int mblk, int nblk, u16* smA, u16* smB,
                                          f32x4 acc[4][4]) {
  const int t = threadIdx.x;
  const int lane = t & 63, wid = t >> 6;
  const int cl = lane & 15, gp = lane >> 4;
  const int r0 = t >> 2, cc = (t & 3) * 8;
  const u16* gA0 = Xg + (size_t)(mblk + r0) * 1024 + cc;
  const u16* gB0 = Wg + (size_t)(nblk + r0) * 1024 + cc;
  u16* lA0 = smA + t * 8;
  u16* lB0 = smB + t * 8;
  const u16* rA = smA + ((wid >> 1) * 64 + cl) * 32 + gp * 8;
  const u16* rB = smB + ((wid & 1) * 64 + cl) * 32 + gp * 8;
  for (int k0 = 0; k0 < 1024; k0 += 32) {
    // issue global loads to regs first: latency overlaps the barrier drain
    bf16x8 sa0 = *(const bf16x8*)(gA0 + k0);
    bf16x8 sa1 = *(const bf16x8*)(gA0 + 64 * 1024 + k0);
    bf16x8 sb0 = *(const bf16x8*)(gB0 + k0);
    bf16x8 sb1 = *(const bf16x8*)(gB0 + 64 * 1024 + k0);
    __syncthreads();  // prev-iter LDS reads complete before overwrite
    *(bf16x8*)lA0 = sa0;
    *(bf16x8*)(lA0 + 2048) = sa1;
    *(bf16x8*)lB0 = sb0;
    *(bf16x8*)(lB0 + 2048) = sb1;
    __syncthreads();  // staging visible to all waves
    bf16x8 a[4], b[4];
#pragma unroll
    for (int i = 0; i < 4; i++) {
      a[i] = *(const bf16x8*)(rA + i * 512);
      b[i] = *(const bf16x8*)(rB + i * 512);
    }
#pragma unroll
    for (int tm = 0; tm < 4; tm++)
#pragma unroll
      for (int tn = 0; tn < 4; tn++) acc[tm][tn] = MFMA(a[tm], b[tn], acc[tm][tn]);
  }
}

// ---------------- fused QKV projection GEMM ----------------
__global__ __launch_bounds__(256) void qkv_gemm(
    const u16* __restrict__ Xb, const u16* __restrict__ Wqb, const u16* __restrict__ Wkb,
    const u16* __restrict__ Wvb, const float* __restrict__ bq, const float* __restrict__ bk,
    const float* __restrict__ bv, u16* __restrict__ Qb, u16* __restrict__ Kb,
    u16* __restrict__ Vt) {
  __shared__ __align__(16) u16 smA[4096], smB[4096];
  const int seg = blockIdx.x >> 3;
  const u16* __restrict__ W = (seg == 0) ? Wqb : (seg == 1) ? Wkb : Wvb;
  const float* __restrict__ bias = (seg == 0) ? bq : (seg == 1) ? bk : bv;
  const int lane = threadIdx.x & 63, wid = threadIdx.x >> 6;
  const int cl = lane & 15, gp = lane >> 4;
  const int mblk = blockIdx.y * 128, nblk = (blockIdx.x & 7) * 128;
  const int m0 = mblk + (wid >> 1) * 64;
  const int n0 = nblk + (wid & 1) * 64;
  f32x4 acc[4][4] = {};
  gemm_core(Xb, W, mblk, nblk, smA, smB, acc);
#pragma unroll
  for (int tn = 0; tn < 4; tn++) {
    int col = n0 + tn * 16 + cl;
    float bv_ = bias[col];
    int hh = col >> 6, dh = col & 63;
#pragma unroll
    for (int tm = 0; tm < 4; tm++) {
#pragma unroll
      for (int r = 0; r < 4; r++) {
        int row = m0 + tm * 16 + gp * 4 + r;
        u16 hv = f2bf(acc[tm][tn][r] + bv_);
        int bb = row >> 11, l = row & 2047;
        if (seg == 0)
          Qb[(((size_t)(bb * 16 + hh) * 2048 + l) << 6) + dh] = hv;
        else if (seg == 1)
          Kb[(((size_t)(bb * 16 + hh) * 2048 + l) << 6) + dh] = hv;
        else
          Vt[((size_t)(bb * 16 + hh) * 64 + dh) * 2048 + l] = hv;
      }
    }
  }
}

// ---------------- out projection GEMM: out = O @ Wo^T + bo (fp32 out) ----------------
__global__ __launch_bounds__(256) void out_gemm(const u16* __restrict__ Xb,
                                                const u16* __restrict__ W,
                                                const float* __restrict__ bias,
                                                float* __restrict__ Y) {
  __shared__ __align__(16) u16 smA[4096], smB[4096];
  const int lane = threadIdx.x & 63, wid = threadIdx.x >> 6;
  const int cl = lane & 15, gp = lane >> 4;
  const int mblk = blockIdx.y * 128, nblk = blockIdx.x * 128;
  const int m0 = mblk + (wid >> 1) * 64;
  const int n0 = nblk + (wid & 1) * 64;
  f32x4 acc[4][4] = {};
  gemm_core(Xb, W, mblk, nblk, smA, smB, acc);
#pragma unroll
  for (int tn = 0; tn < 4; tn++) {
    int col = n0 + tn * 16 + cl;
    float bv_ = bias[col];
#pragma unroll
    for (int tm = 0; tm < 4; tm++)
#pragma unroll
      for (int r = 0; r < 4; r++) {
        int row = m0 + tm * 16 + gp * 4 + r;
        Y[(size_t)row * 1024 + col] = acc[tm][tn][r] + bv_;
      }
  }
}

// ---------------- fused flash attention: pass1 (m,l) + pass2 (attn write + PV) ----------------
// wave handles 16 queries; block = 64 queries of one (b,h)
__global__ __launch_bounds__(256) void flash_fused(const u16* __restrict__ Qb,
                                                   const u16* __restrict__ Kb,
                                                   const u16* __restrict__ Vt,
                                                   const float* __restrict__ sal,
                                                   float* __restrict__ attn,
                                                   u16* __restrict__ Ob) {
  __shared__ __align__(16) u16 pbuf[4][16][72];  // per-wave 16x64 P tile, padded stride 72
  const int bh = blockIdx.x;
  const int b = bh >> 4, h = bh & 15;
  const int lane = threadIdx.x & 63, wid = threadIdx.x >> 6;
  const int cl = lane & 15, gp = lane >> 4;
  const int q0 = blockIdx.y * 64 + wid * 16;
  const u16* Qh = Qb + (size_t)bh * 2048 * 64;
  const u16* Kh = Kb + (size_t)bh * 2048 * 64;
  const u16* Vh = Vt + (size_t)bh * 64 * 2048;
  const float* salh = sal + bh * 2048;
  bf16x8 aQ0 = *(const bf16x8*)(Qh + (size_t)(q0 + cl) * 64 + gp * 8);
  bf16x8 aQ1 = *(const bf16x8*)(Qh + (size_t)(q0 + cl) * 64 + 32 + gp * 8);
  float m[4], l[4];
#pragma unroll
  for (int r = 0; r < 4; r++) { m[r] = -1e30f; l[r] = 0.f; }

  // ---- pass 1: QK^T -> running (m, l). No PV, no LDS, no barriers.
  for (int kb = 0; kb < 2048; kb += 64) {
    f32x4 st[4];
#pragma unroll
    for (int tn = 0; tn < 4; tn++) {
      const u16* kp = Kh + (size_t)(kb + tn * 16 + cl) * 64 + gp * 8;
      f32x4 s = {};
      s = MFMA(aQ0, *(const bf16x8*)kp, s);
      s = MFMA(aQ1, *(const bf16x8*)(kp + 32), s);
      st[tn] = s;
    }
#pragma unroll
    for (int tn = 0; tn < 4; tn++) {
      float sv = salh[kb + tn * 16 + cl];
#pragma unroll
      for (int r = 0; r < 4; r++) st[tn][r] = st[tn][r] * 0.125f + sv;
    }
#pragma unroll
    for (int r = 0; r < 4; r++) {
      float v = fmaxf(fmaxf(st[0][r], st[1][r]), fmaxf(st[2][r], st[3][r]));
      v = fmaxf(v, __shfl_xor(v, 1));
      v = fmaxf(v, __shfl_xor(v, 2));
      v = fmaxf(v, __shfl_xor(v, 4));
      v = fmaxf(v, __shfl_xor(v, 8));
      float mn = fmaxf(m[r], v);
      float alpha = __expf(m[r] - mn);
      m[r] = mn;
      float s0 = 0.f;
#pragma unroll
      for (int tn = 0; tn < 4; tn++) s0 += __expf(st[tn][r] - mn);
      s0 += __shfl_xor(s0, 1);
      s0 += __shfl_xor(s0, 2);
      s0 += __shfl_xor(s0, 4);
      s0 += __shfl_xor(s0, 8);
      l[r] = l[r] * alpha + s0;
    }
  }
  float il[4];
#pragma unroll
  for (int r = 0; r < 4; r++) il[r] = 1.0f / l[r];

  // ---- pass 2: recompute S, write normalized attn, accumulate O (final m,l -> no rescale)
  f32x4 oacc[4] = {};
  float* arow = attn + (size_t)bh * 2048 * 2048;
  u16* pw = &pbuf[wid][0][0];
  for (int kb = 0; kb < 2048; kb += 64) {
    f32x4 st[4];
#pragma unroll
    for (int tn = 0; tn < 4; tn++) {
      const u16* kp = Kh + (size_t)(kb + tn * 16 + cl) * 64 + gp * 8;
      f32x4 s = {};
      s = MFMA(aQ0, *(const bf16x8*)kp, s);
      s = MFMA(aQ1, *(const bf16x8*)(kp + 32), s);
      st[tn] = s;
    }
#pragma unroll
    for (int tn = 0; tn < 4; tn++) {
      float sv = salh[kb + tn * 16 + cl];
#pragma unroll
      for (int r = 0; r < 4; r++) {
        float p = __expf(st[tn][r] * 0.125f + sv - m[r]);
        arow[(size_t)(q0 + gp * 4 + r) * 2048 + kb + tn * 16 + cl] = p * il[r];
        pw[(gp * 4 + r) * 72 + tn * 16 + cl] = f2bf(p);
      }
    }
    __syncthreads();
    bf16x8 aP0 = *(const bf16x8*)(pw + cl * 72 + gp * 8);
    bf16x8 aP1 = *(const bf16x8*)(pw + cl * 72 + 32 + gp * 8);
#pragma unroll
    for (int tn = 0; tn < 4; tn++) {
      const u16* vp = Vh + (size_t)(tn * 16 + cl) * 2048 + kb + gp * 8;
      oacc[tn] = MFMA(aP0, *(const bf16x8*)vp, oacc[tn]);
      oacc[tn] = MFMA(aP1, *(const bf16x8*)(vp + 32), oacc[tn]);
    }
    __syncthreads();
  }
#pragma unroll
  for (int tn = 0; tn < 4; tn++) {
    int d = h * 64 + tn * 16 + cl;
#pragma unroll
    for (int r = 0; r < 4; r++) {
      int q = q0 + gp * 4 + r;
      Ob[((size_t)(b * 2048 + q)) * 1024 + d] = f2bf(oacc[tn][r] * il[r]);
    }
  }
}

// ---------------- launch ----------------
extern "C" void kernel_launch(void* const* d_in, const int* in_sizes, int n_in,
                              void* d_out, int out_size, void* d_ws, size_t ws_size,
                              hipStream_t stream) {
  const float* src = (const float*)d_in[0];
  const float* Wq = (const float*)d_in[1];
  const float* bq = (const float*)d_in[2];
  const float* Wk = (const float*)d_in[3];
  const float* bk = (const float*)d_in[4];
  const float* Wv = (const float*)d_in[5];
  const float* bv = (const float*)d_in[6];
  const float* Wo = (const float*)d_in[7];
  const float* bo = (const float*)d_in[8];
  const float* cw = (const float*)d_in[9];
  const float* cb = (const float*)d_in[10];

  char* ws = (char*)d_ws;
  u16* srcb = (u16*)(ws + 0);          // 8,388,608 B
  u16* wqb = (u16*)(ws + 8388608);     // 2,097,152 B
  u16* wkb = (u16*)(ws + 10485760);
  u16* wvb = (u16*)(ws + 12582912);
  u16* wob = (u16*)(ws + 14680064);
  u16* Qb = (u16*)(ws + 16777216);     // 8,388,608 B  [B,H,L,64] bf16
  u16* Kb = (u16*)(ws + 25165824);
  u16* Vt = (u16*)(ws + 33554432);     // [B,H,64,L] bf16
  u16* Ob = (u16*)(ws + 41943040);     // [B,L,D] bf16
  float* cwT = (float*)(ws + 50331648);
  float* sal = (float*)(ws + 50528256);  // end 50,790,400

  float* outp = (float*)d_out;
  float* attn = (float*)d_out + 4194304;

  prep_all<<<8384, 256, 0, stream>>>((const float4*)src, (const float4*)Wq, (const float4*)Wk,
                                     (const float4*)Wv, (const float4*)Wo, cw,
                                     (uint2*)srcb, (uint2*)wqb, (uint2*)wkb, (uint2*)wvb,
                                     (uint2*)wob, cwT);
  conv_sal_k<<<dim3(128, 2), 256, 0, stream>>>(src, cwT, cb, sal);
  qkv_gemm<<<dim3(24, 32), 256, 0, stream>>>(srcb, wqb, wkb, wvb, bq, bk, bv, Qb, Kb, Vt);
  flash_fused<<<dim3(32, 32), 256, 0, stream>>>(Qb, Kb, Vt, sal, attn, Ob);
  out_gemm<<<dim3(8, 32), 256, 0, stream>>>(Ob, wob, bo, outp);
}